// Round 11
// baseline (2536.612 us; speedup 1.0000x reference)
//
#include <hip/hip_runtime.h>

#define NP 20000
#define NC 80000
#define NN 100000
#define NE 1600000
#define HD 128
#define BKT 391   // buckets of 256 nodes
#define BINB 391  // bin blocks, 4096 edges each
#define NSUB (BKT * 4)  // 64-dst sub-buckets = 1564
#define NCHK 13         // src chunks of 8192 rows (2 MB of h) each

// Timing model: ~107 us fixed harness overhead/iter. R10=296: C=107 |
// agg_sage 2x69.2 | graph ~51. Gather pinned at ~3.6 TB/s L3 random path;
// this round: src-chunked LDS-accumulator aggregation for L2 locality.

typedef unsigned short ushort_t;
typedef unsigned int uint_t;

typedef __attribute__((ext_vector_type(8))) short bf16x8;
typedef __attribute__((ext_vector_type(4))) float f32x4;

// fp32 -> bf16 RNE
__device__ __forceinline__ ushort_t f2bf(float f) {
  uint_t u = __builtin_bit_cast(uint_t, f);
  u = (u + 0x7FFF + ((u >> 16) & 1)) >> 16;
  return (ushort_t)u;
}
__device__ __forceinline__ float b2f(ushort_t u) {
  return __builtin_bit_cast(float, (uint_t)u << 16);
}
__device__ __forceinline__ uint4 pack8(float4 lo, float4 hi) {
  ushort_t t[8];
  t[0] = f2bf(lo.x); t[1] = f2bf(lo.y); t[2] = f2bf(lo.z); t[3] = f2bf(lo.w);
  t[4] = f2bf(hi.x); t[5] = f2bf(hi.y); t[6] = f2bf(hi.z); t[7] = f2bf(hi.w);
  return *(uint4*)t;
}

// pack one task of W (fp32, K x 128) into bf16 B-fragment order, K padded
// with zeros to KB*32. task in [0, 8*KB*64). P idx = task*8 + j.
__device__ __forceinline__ void pack_tile(const float* __restrict__ W,
                                          ushort_t* __restrict__ P, int KF,
                                          int KB, int task) {
  int t = task / (KB * 64);
  int rem = task - t * KB * 64;
  int kb = rem >> 6;
  int lane = rem & 63;
  int k0 = kb * 32 + ((lane >> 4) << 3);
  int c = t * 16 + (lane & 15);
  ushort_t tmp[8];
#pragma unroll
  for (int j = 0; j < 8; ++j) {
    int k = k0 + j;
    tmp[j] = (k < KF) ? f2bf(W[(size_t)k * HD + c]) : (ushort_t)0;
  }
  *(uint4*)(P + (size_t)task * 8) = *(uint4*)tmp;
}

// ---------------- prep: per-block bucket histogram + all W packs ----------
#define PACKB 46  // 4x8 (sage) + 8 (Wcomp K=128) + 6 (Wpol K=96)
__global__ __launch_bounds__(256) void prep_k(
    const int* __restrict__ dst, int* __restrict__ hist2t,
    const float* __restrict__ Wl1, const float* __restrict__ Wr1,
    const float* __restrict__ Wl2, const float* __restrict__ Wr2,
    const float* __restrict__ W_comp, const float* __restrict__ W_pol,
    ushort_t* __restrict__ wl1p, ushort_t* __restrict__ wr1p,
    ushort_t* __restrict__ wl2p, ushort_t* __restrict__ wr2p,
    ushort_t* __restrict__ wcompp, ushort_t* __restrict__ wpolp) {
  __shared__ int hist[BKT];
  int blk = blockIdx.x;
  int tid = threadIdx.x;
  if (blk < BINB) {
    for (int t = tid; t < BKT; t += 256) hist[t] = 0;
    __syncthreads();
    int base = blk * 4096;
#pragma unroll
    for (int q = 0; q < 16; ++q) {
      int e = base + q * 256 + tid;
      if (e < NE) atomicAdd(&hist[dst[e] >> 8], 1);
    }
    __syncthreads();
    for (int t = tid; t < BKT; t += 256)
      hist2t[(size_t)t * BINB + blk] = hist[t];
    return;
  }
  int pb = blk - BINB;
  if (pb < 8) pack_tile(Wl1, wl1p, 128, 4, pb * 256 + tid);
  else if (pb < 16) pack_tile(Wr1, wr1p, 128, 4, (pb - 8) * 256 + tid);
  else if (pb < 24) pack_tile(Wl2, wl2p, 128, 4, (pb - 16) * 256 + tid);
  else if (pb < 32) pack_tile(Wr2, wr2p, 128, 4, (pb - 24) * 256 + tid);
  else if (pb < 40) pack_tile(W_comp, wcompp, 112, 4, (pb - 32) * 256 + tid);
  else pack_tile(W_pol, wpolp, 72, 3, (pb - 40) * 256 + tid);
}

// ------- scanA: per-bucket exclusive prefix over blocks (wave scan) -------
__global__ __launch_bounds__(64) void scanA_k(int* __restrict__ hist2t,
                                              int* __restrict__ bcnt) {
  int t = blockIdx.x;
  int lane = threadIdx.x;
  int* base = hist2t + (size_t)t * BINB;
  int carry = 0;
  for (int c = 0; c < 7; ++c) {  // 7*64 = 448 >= BINB
    int i = c * 64 + lane;
    int orig = (i < BINB) ? base[i] : 0;
    int v = orig;
#pragma unroll
    for (int off = 1; off < 64; off <<= 1) {
      int u = __shfl_up(v, off);
      if (lane >= off) v += u;
    }
    if (i < BINB) base[i] = v - orig + carry;
    carry += __shfl(v, 63);
  }
  if (lane == 0) bcnt[t] = carry;
}

// ---------------- scanB: exclusive scan of bucket totals ----------------
__global__ __launch_bounds__(512) void scan_k(const int* __restrict__ bcnt,
                                              int* __restrict__ bstart) {
  __shared__ int s[512];
  int t = threadIdx.x;
  int v = (t < BKT) ? bcnt[t] : 0;
  s[t] = v;
  __syncthreads();
  for (int off = 1; off < 512; off <<= 1) {
    int x = (t >= off) ? s[t - off] : 0;
    __syncthreads();
    s[t] += x;
    __syncthreads();
  }
  if (t < BKT) bstart[t] = s[t] - v;
}

// ---------------- bin edges + MFMA encoders (fused, independent) -----------
// Keep the staged LDS sort (R7: dropping it cost +9 us). Deterministic
// gbase (R4, no global atomic chains).
#define COMP_E (NC / 128)        // 625 blocks, 128 nodes each
#define POL_E ((NP + 127) / 128) // 157
__global__ __launch_bounds__(512) void bin_enc_k(
    const int* __restrict__ src, const int* __restrict__ dst,
    const int* __restrict__ bstart, const int* __restrict__ hist2t,
    uint_t* __restrict__ ebuf,
    const float* __restrict__ x_comp, const int* __restrict__ sec,
    const int* __restrict__ ind, const float* __restrict__ semb,
    const float* __restrict__ iemb, const ushort_t* __restrict__ wcompp,
    const float* __restrict__ b_comp,
    const float* __restrict__ x_pol, const int* __restrict__ sidx,
    const float* __restrict__ stemb, const ushort_t* __restrict__ wpolp,
    const float* __restrict__ b_pol,
    ushort_t* __restrict__ h0) {
  __shared__ int hist[BKT];
  __shared__ int lscan[BKT];
  __shared__ int gbase[BKT];
  __shared__ int sv[512];
  __shared__ uint2 stage[4096];
  int blk = blockIdx.x;
  int tid = threadIdx.x;

  if (blk < BINB) {
    // ---- counting-sort 4096 edges into bucket-grouped ebuf ----
    for (int t = tid; t < BKT; t += 512) hist[t] = 0;
    __syncthreads();
    int base = blk * 4096;
    int cntE = min(4096, NE - base);
    int ss[8], dd[8], rr[8];
#pragma unroll
    for (int q = 0; q < 8; ++q) {
      int e = base + q * 512 + tid;
      if (e < NE) {
        dd[q] = dst[e];
        ss[q] = src[e];
        rr[q] = atomicAdd(&hist[dd[q] >> 8], 1);
      } else {
        dd[q] = -1;
      }
    }
    __syncthreads();
    int hv = (tid < BKT) ? hist[tid] : 0;
    sv[tid] = hv;
    __syncthreads();
    for (int off = 1; off < 512; off <<= 1) {
      int x = (tid >= off) ? sv[tid - off] : 0;
      __syncthreads();
      sv[tid] += x;
      __syncthreads();
    }
    if (tid < BKT) {
      lscan[tid] = sv[tid] - hv;
      gbase[tid] = bstart[tid] + hist2t[(size_t)tid * BINB + blk];
    }
    __syncthreads();
#pragma unroll
    for (int q = 0; q < 8; ++q) {
      if (dd[q] >= 0) {
        int bb = dd[q] >> 8;
        stage[lscan[bb] + rr[q]] = make_uint2((uint_t)ss[q], (uint_t)dd[q]);
      }
    }
    __syncthreads();
    for (int j = tid; j < cntE; j += 512) {
      uint2 v = stage[j];
      int bb = v.y >> 8;
      ebuf[gbase[bb] + (j - lscan[bb])] = (v.x << 8) | (v.y & 255u);
    }
    return;
  }
  int lane = tid & 63;
  int wv = tid >> 6;
  int n16 = lane & 15, quad = lane >> 4;
  if (blk < BINB + COMP_E) {
    // ---- comp encoder via MFMA: h = relu([x|sec|ind|0pad] @ Wc + bc) ----
    int rowbase = (blk - BINB) * 128 + wv * 16;
    int node = rowbase + n16;
    const float4* xr = (const float4*)(x_comp + (size_t)node * 96);
    uint4 a[4];
#pragma unroll
    for (int kb = 0; kb < 3; ++kb) {
      float4 lo = xr[kb * 8 + quad * 2], hi = xr[kb * 8 + quad * 2 + 1];
      a[kb] = pack8(lo, hi);
    }
    if (quad == 0) {
      const float4* er = (const float4*)(semb + (size_t)sec[node] * 8);
      a[3] = pack8(er[0], er[1]);
    } else if (quad == 1) {
      const float4* er = (const float4*)(iemb + (size_t)ind[node] * 8);
      a[3] = pack8(er[0], er[1]);
    } else {
      a[3] = make_uint4(0, 0, 0, 0);
    }
    const bf16x8* W = (const bf16x8*)wcompp;
    ushort_t* hb = h0 + (size_t)NP * HD;
#pragma unroll
    for (int t = 0; t < 8; ++t) {
      float bias = b_comp[t * 16 + n16];
      f32x4 acc = {bias, bias, bias, bias};
#pragma unroll
      for (int kb = 0; kb < 4; ++kb)
        acc = __builtin_amdgcn_mfma_f32_16x16x32_bf16(
            __builtin_bit_cast(bf16x8, a[kb]), W[(t * 4 + kb) * 64 + lane],
            acc, 0, 0, 0);
      int r0 = rowbase + quad * 4;
      int c = t * 16 + n16;
#pragma unroll
      for (int r = 0; r < 4; ++r)
        hb[(size_t)(r0 + r) * HD + c] = f2bf(fmaxf(acc[r], 0.f));
    }
    return;
  }
  {
    // ---- pol encoder via MFMA: h = relu([x|state|0pad] @ Wp + bp) ----
    int rowbase = (blk - BINB - COMP_E) * 128 + wv * 16;
    if (rowbase >= NP) return;
    int node = rowbase + n16;
    const float4* xr = (const float4*)(x_pol + (size_t)node * 64);
    uint4 a[3];
#pragma unroll
    for (int kb = 0; kb < 2; ++kb) {
      float4 lo = xr[kb * 8 + quad * 2], hi = xr[kb * 8 + quad * 2 + 1];
      a[kb] = pack8(lo, hi);
    }
    if (quad == 0) {
      const float4* er = (const float4*)(stemb + (size_t)sidx[node] * 8);
      a[2] = pack8(er[0], er[1]);
    } else {
      a[2] = make_uint4(0, 0, 0, 0);
    }
    const bf16x8* W = (const bf16x8*)wpolp;
#pragma unroll
    for (int t = 0; t < 8; ++t) {
      float bias = b_pol[t * 16 + n16];
      f32x4 acc = {bias, bias, bias, bias};
#pragma unroll
      for (int kb = 0; kb < 3; ++kb)
        acc = __builtin_amdgcn_mfma_f32_16x16x32_bf16(
            __builtin_bit_cast(bf16x8, a[kb]), W[(t * 3 + kb) * 64 + lane],
            acc, 0, 0, 0);
      int r0 = rowbase + quad * 4;
      int c = t * 16 + n16;
#pragma unroll
      for (int r = 0; r < 4; ++r)
        h0[(size_t)(r0 + r) * HD + c] = f2bf(fmaxf(acc[r], 0.f));
    }
  }
}

// ------- sortb: within each 256-bucket, sort edges by (64-sub, src-chunk) --
// Gives agg_sage2 (a) per-64-dst edge ranges (CSR build_k deleted) and
// (b) ascending-src-chunk order so concurrent blocks walk the h table in
// rough lockstep (2 MB windows -> L2-resident).
__global__ __launch_bounds__(512) void sortb_k(uint_t* __restrict__ ebuf,
                                               const int* __restrict__ bstart,
                                               const int* __restrict__ bcnt,
                                               int* __restrict__ substart,
                                               int* __restrict__ subcnt) {
  __shared__ uint_t s2[4608];
  __shared__ int h[52];
  __shared__ int hs[53];
  int b = blockIdx.x, tid = threadIdx.x;
  int st = bstart[b];
  int cb = min(bcnt[b], 4608);  // mean 4092, sd 64 -> 8-sigma margin
  for (int k = tid; k < 52; k += 512) h[k] = 0;
  __syncthreads();
  uint_t vv[9];
  int kk[9], rr[9], n = 0;
  for (int j = tid; j < cb; j += 512) {
    uint_t v = ebuf[st + j];
    // v = (src<<8)|(dst&255); sub = (dst>>6)&3; chunk = src>>13 in [0,12]
    int key = (int)((v >> 6) & 3u) * NCHK + (int)(v >> 21);
    vv[n] = v;
    kk[n] = key;
    rr[n] = atomicAdd(&h[key], 1);
    ++n;
  }
  __syncthreads();
  if (tid == 0) {
    int acc = 0;
    for (int k = 0; k < 52; ++k) { hs[k] = acc; acc += h[k]; }
    hs[52] = acc;
  }
  __syncthreads();
  for (int i = 0; i < n; ++i) s2[hs[kk[i]] + rr[i]] = vv[i];
  __syncthreads();
  for (int j = tid; j < cb; j += 512) ebuf[st + j] = s2[j];
  if (tid < 4) {
    int s0 = hs[tid * NCHK];
    int s1 = (tid < 3) ? hs[(tid + 1) * NCHK] : cb;
    substart[b * 4 + tid] = st + s0;
    subcnt[b * 4 + tid] = s1 - s0;
  }
}

// ------- fused aggregation (src-chunked, LDS f32 accum) + SAGE MFMA -------
// Block = 64 dsts. Phase 1: walk this sub-bucket's edges in src-chunk order;
// per edge, wave reads the 256B src row (coalesced) and LDS-atomicAdds into
// macc[64][132] (lane->col l and l+64: 2-way banks, free). Exact per-dst
// count in lcnt (no MAXDEG cap). Phase 2 = R10's proven slab MFMA, means
// read straight from LDS (m never touches HBM, CSR col never built).
__global__ __launch_bounds__(512) void agg_sage2_k(
    const ushort_t* __restrict__ hbf, const uint_t* __restrict__ ebuf,
    const int* __restrict__ substart, const int* __restrict__ subcnt,
    const ushort_t* __restrict__ Wlp, const float* __restrict__ bl,
    const ushort_t* __restrict__ Wrp, float* __restrict__ outf,
    ushort_t* __restrict__ outb, int relu) {
  __shared__ float macc[64][132];  // +4 pad: atomic/read banks 2-way
  __shared__ int lcnt[64];
  __shared__ __align__(16) ushort_t lh[64][136];
  int tid = threadIdx.x;
  int lane = tid & 63, wv = tid >> 6;
  int g = blockIdx.x;
  int base = g * 64;

  for (int i = tid; i < 64 * 132; i += 512) ((float*)macc)[i] = 0.f;
  if (tid < 64) lcnt[tid] = 0;
  // stage own-h tile (guarded: last sub-buckets exceed NN)
  const uint4* hrow4 = (const uint4*)hbf;
  for (int i = tid; i < 1024; i += 512) {
    int row = i >> 4, ch = i & 15;
    uint4 gv = (base + row < NN) ? hrow4[(size_t)(base + row) * 16 + ch]
                                 : make_uint4(0, 0, 0, 0);
    *(uint4*)&lh[row][ch * 8] = gv;
  }
  __syncthreads();

  int est = substart[g], ecnt = subcnt[g];
  for (int e0 = wv * 8; e0 < ecnt; e0 += 64) {
    uint_t vv[8];
    ushort_t r0[8], r1[8];
#pragma unroll
    for (int u = 0; u < 8; ++u) {
      int e = e0 + u;
      vv[u] = (e < ecnt) ? ebuf[est + e] : 0xFFFFFFFFu;
    }
#pragma unroll
    for (int u = 0; u < 8; ++u) {
      if (vv[u] != 0xFFFFFFFFu) {
        const ushort_t* rp = hbf + (size_t)(vv[u] >> 8) * HD;
        r0[u] = rp[lane];
        r1[u] = rp[lane + 64];
      }
    }
#pragma unroll
    for (int u = 0; u < 8; ++u) {
      if (vv[u] != 0xFFFFFFFFu) {
        int local = (int)(vv[u] & 63u);
        atomicAdd(&macc[local][lane], b2f(r0[u]));
        atomicAdd(&macc[local][lane + 64], b2f(r1[u]));
        if (lane == 0) atomicAdd(&lcnt[local], 1);
      }
    }
  }
  __syncthreads();

  // ---- phase 2: wave = 16-row group x 64-col half ----
  int n16 = lane & 15, quad = lane >> 4;
  int rb = (wv & 3) * 16;
  int ct = (wv >> 2) * 4;  // 4 t-tiles of 16 cols
  int rl = rb + n16;
  float inv = 1.f / (float)max(lcnt[rl], 1);
  uint4 am[4], ah[4];
#pragma unroll
  for (int kb = 0; kb < 4; ++kb) {
    int k0 = kb * 32 + quad * 8;
    float4 lo = make_float4(macc[rl][k0] * inv, macc[rl][k0 + 1] * inv,
                            macc[rl][k0 + 2] * inv, macc[rl][k0 + 3] * inv);
    float4 hi = make_float4(macc[rl][k0 + 4] * inv, macc[rl][k0 + 5] * inv,
                            macc[rl][k0 + 6] * inv, macc[rl][k0 + 7] * inv);
    am[kb] = pack8(lo, hi);
    ah[kb] = *(const uint4*)&lh[rl][(kb * 4 + quad) * 8];
  }
  const bf16x8* WL = (const bf16x8*)Wlp;
  const bf16x8* WR = (const bf16x8*)Wrp;
#pragma unroll
  for (int t = ct; t < ct + 4; ++t) {
    float bias = bl[t * 16 + n16];
    f32x4 acc = {bias, bias, bias, bias};
#pragma unroll
    for (int kb = 0; kb < 4; ++kb)
      acc = __builtin_amdgcn_mfma_f32_16x16x32_bf16(
          __builtin_bit_cast(bf16x8, am[kb]), WL[(t * 4 + kb) * 64 + lane],
          acc, 0, 0, 0);
#pragma unroll
    for (int kb = 0; kb < 4; ++kb)
      acc = __builtin_amdgcn_mfma_f32_16x16x32_bf16(
          __builtin_bit_cast(bf16x8, ah[kb]), WR[(t * 4 + kb) * 64 + lane],
          acc, 0, 0, 0);
    int rr0 = base + rb + quad * 4;
    int c = t * 16 + n16;
#pragma unroll
    for (int r = 0; r < 4; ++r) {
      if (rr0 + r < NN) {
        float v = acc[r];
        if (relu) v = fmaxf(v, 0.f);
        if (outb)
          outb[(size_t)(rr0 + r) * HD + c] = f2bf(v);
        else
          outf[(size_t)(rr0 + r) * HD + c] = v;
      }
    }
  }
}

extern "C" void kernel_launch(void* const* d_in, const int* in_sizes, int n_in,
                              void* d_out, int out_size, void* d_ws,
                              size_t ws_size, hipStream_t stream) {
  const float* x_pol = (const float*)d_in[0];
  const int* pol_state_idx = (const int*)d_in[1];
  const float* x_comp = (const float*)d_in[2];
  const int* comp_sector = (const int*)d_in[3];
  const int* comp_ind = (const int*)d_in[4];
  const float* state_emb = (const float*)d_in[6];
  const float* sector_emb = (const float*)d_in[7];
  const float* ind_emb = (const float*)d_in[8];
  const float* W_pol = (const float*)d_in[9];
  const float* b_pol = (const float*)d_in[10];
  const float* W_comp = (const float*)d_in[11];
  const float* b_comp = (const float*)d_in[12];
  const float* Wl1 = (const float*)d_in[13];
  const float* bl1 = (const float*)d_in[14];
  const float* Wr1 = (const float*)d_in[15];
  const float* Wl2 = (const float*)d_in[16];
  const float* bl2 = (const float*)d_in[17];
  const float* Wr2 = (const float*)d_in[18];

  const int* src = (const int*)d_in[5];         // edge_index[0]
  const int* dst = ((const int*)d_in[5]) + NE;  // edge_index[1]

  // ws: h0 | h1 | ebuf[NE] | packed W x6 | bcnt | bstart | hist2t |
  //     substart[NSUB] | subcnt[NSUB]   ~59 MB
  const size_t HBYTES = (size_t)NN * HD * sizeof(ushort_t);  // 25.6 MB
  char* ws = (char*)d_ws;
  ushort_t* h0_bf = (ushort_t*)ws;
  ushort_t* h1_bf = (ushort_t*)(ws + HBYTES);
  uint_t* ebuf = (uint_t*)(ws + 2 * HBYTES);
  ushort_t* wl1p = (ushort_t*)(ebuf + NE);  // 16384 elems each (K=128)
  ushort_t* wr1p = wl1p + 16384;
  ushort_t* wl2p = wr1p + 16384;
  ushort_t* wr2p = wl2p + 16384;
  ushort_t* wcompp = wr2p + 16384;   // 16384 (K padded to 128)
  ushort_t* wpolp = wcompp + 16384;  // 12288 (K padded to 96)
  int* bcnt = (int*)(wpolp + 12288);
  int* bstart = bcnt + BKT;
  int* hist2t = bstart + BKT;        // [BKT][BINB] = 611 KB
  int* substart = hist2t + BKT * BINB;
  int* subcnt = substart + NSUB;

  float* out_f = (float*)d_out;

  // chain: hist -> block-prefix scan -> total scan -> staged bin+encoders ->
  // sub-bucket/src-chunk sort -> fused agg+sage x2 (no CSR, no m buffer)
  prep_k<<<BINB + PACKB, 256, 0, stream>>>(dst, hist2t, Wl1, Wr1, Wl2, Wr2,
                                           W_comp, W_pol, wl1p, wr1p, wl2p,
                                           wr2p, wcompp, wpolp);
  scanA_k<<<BKT, 64, 0, stream>>>(hist2t, bcnt);
  scan_k<<<1, 512, 0, stream>>>(bcnt, bstart);
  bin_enc_k<<<BINB + COMP_E + POL_E, 512, 0, stream>>>(
      src, dst, bstart, hist2t, ebuf, x_comp, comp_sector, comp_ind,
      sector_emb, ind_emb, wcompp, b_comp, x_pol, pol_state_idx, state_emb,
      wpolp, b_pol, h0_bf);
  sortb_k<<<BKT, 512, 0, stream>>>(ebuf, bstart, bcnt, substart, subcnt);

  // layer 1: h1 = relu(mean-aggr(h0)@Wl1 + bl1 + h0@Wr1)  (bf16 out)
  agg_sage2_k<<<NSUB, 512, 0, stream>>>(h0_bf, ebuf, substart, subcnt, wl1p,
                                        bl1, wr1p, nullptr, h1_bf, 1);
  // layer 2: out = mean-aggr(h1)@Wl2 + bl2 + h1@Wr2  (fp32 out)
  agg_sage2_k<<<NSUB, 512, 0, stream>>>(h1_bf, ebuf, substart, subcnt, wl2p,
                                        bl2, wr2p, out_f, nullptr, 0);
}